// Round 9
// baseline (2595.478 us; speedup 1.0000x reference)
//
#include <hip/hip_runtime.h>

// HyperNetSIR: x(N,3) f32, H(E,N) f32 0/1 mask (density 0.002), beta(N), gamma(N), steps(int)
// out: (steps, N, 3) f32 trajectory.
//
// v9 — SLOT-SCATTER DATAFLOW, zero barriers:
//  Calibration from rounds 2-8: one cross-XCD (IF) round trip ~1.25us; v4's
//  9.9us/step == its 8-hop serial chain (gather, drain, arrive, detect, x2).
//  v8 showed agent-atomic RMWs stream 64B lines to HBM (bound at 326MB writes).
//  v9 removes ALL barriers: write-once per-step slot buffers, sentinel -1.0
//  prefilled (legit values >= 0). Producers sc-store values into consumers'
//  CONTIGUOUS slots; consumers poll their own 1-6 cache lines until every
//  valid slot is non-negative (value IS the ready flag; write-once => any
//  ready value is final). Per step: store-visible + poll-detect, twice
//  (~4 RT vs 8), steps pipeline across blocks (no global skew max).
//   - edgeIn[t][e][0..95]: I-values of edge e's members, written by node
//     owners at positions fixed at build; edge group (16 lanes) polls lanes'
//     stride-16 slots => 6 coalesced line-requests per round.
//   - nodeIn[t][n][0..31]: y-values of node n's edges at build-fixed slots;
//     node thread polls its own 1-2 lines.
//   - summation orders identical to v4 (lane-strided edge sum, shfl_down
//     reduce, lane0 value broadcast; node z in slot order 0..ncnt-1).
//   - no __syncthreads in the solve => threads may early-exit; dependency
//     step index strictly decreases along any wait chain => deadlock-free.
//  build: v6 two-pass, writeout now emits slot targets (edge_tgt/node_tgt).

#define EDGE_CAP 96   // max nodes per edge (mean 40, sigma 6.3)
#define NODE_CAP 32   // max edges per node (mean 10, sigma 3.2)
#define COOP_BLOCKS 128
#define COOP_THREADS 640   // 40 edge-groups x 16 lanes; node_chunk 157 <= 640

typedef unsigned int uint4_ev __attribute__((ext_vector_type(4)));
typedef float float4_ev __attribute__((ext_vector_type(4)));

// Sentinel-fill the slot buffers (float4 grid-stride) + zero the counters.
__global__ void init_ws_kernel(int* edge_cnt, int* node_cnt,
                               float4_ev* sent, long long n_sent4,
                               int n_edges, int n_nodes) {
    long long i = (long long)blockIdx.x * blockDim.x + threadIdx.x;
    long long stride = (long long)gridDim.x * blockDim.x;
    const float4_ev mone = {-1.0f, -1.0f, -1.0f, -1.0f};
    for (long long k = i; k < n_sent4; k += stride) sent[k] = mone;
    if (i < n_edges) edge_cnt[i] = 0;
    if (i < n_nodes) node_cnt[i] = 0;
}

// One block (256 threads) per edge row (v6 two-pass scan).
// Writeout now records SLOT TARGETS both ways:
//   edge_tgt[e][i] = c*NODE_CAP + q  (where edge e stores y for member c)
//   node_tgt[c][q] = e*EDGE_CAP + i  (where node c stores I for edge e)
__global__ void build_adjacency_kernel(const float* __restrict__ H,
                                       int* __restrict__ edge_cnt,
                                       int* __restrict__ edge_tgt,
                                       int* __restrict__ node_cnt,
                                       int* __restrict__ node_tgt,
                                       int n_nodes) {
    __shared__ int cnt;
    __shared__ int cols[EDGE_CAP];
    __shared__ unsigned long long qmask[128];   // supports n_nodes <= 32768
    const int e  = blockIdx.x;
    const int tx = threadIdx.x;
    if (tx == 0) cnt = 0;
    const float* row = H + (size_t)e * n_nodes;
    const uint4_ev* row4 = (const uint4_ev*)row;
    const int n4 = n_nodes >> 2;
    const int niter = (n4 + 255) >> 8;

    for (int i = 0; i < niter; ++i) {
        int q = (i << 8) + tx;
        uint4_ev v = {0u, 0u, 0u, 0u};
        if (q < n4) v = row4[q];
        unsigned long long m = __ballot((v.x | v.y | v.z | v.w) != 0u);
        if ((tx & 63) == 0) qmask[(i << 2) + (tx >> 6)] = m;
    }
    __syncthreads();

    const int nslots = niter << 2;
    for (int sIdx = tx; sIdx < nslots; sIdx += blockDim.x) {
        unsigned long long m = qmask[sIdx];
        int qbase = ((sIdx >> 2) << 8) + ((sIdx & 3) << 6);
        while (m) {
            int lane = __builtin_ctzll(m); m &= m - 1;
            int q = qbase + lane;
            uint4_ev v = row4[q];               // L2 hit
            int cbase = q << 2;
            if (v.x) { int p = atomicAdd(&cnt, 1); if (p < EDGE_CAP) cols[p] = cbase; }
            if (v.y) { int p = atomicAdd(&cnt, 1); if (p < EDGE_CAP) cols[p] = cbase + 1; }
            if (v.z) { int p = atomicAdd(&cnt, 1); if (p < EDGE_CAP) cols[p] = cbase + 2; }
            if (v.w) { int p = atomicAdd(&cnt, 1); if (p < EDGE_CAP) cols[p] = cbase + 3; }
        }
    }
    if (tx == 0) {   // tail (n_nodes not multiple of 4)
        for (int c = n4 << 2; c < n_nodes; ++c)
            if (row[c] != 0.0f) { int p = atomicAdd(&cnt, 1); if (p < EDGE_CAP) cols[p] = c; }
    }
    __syncthreads();

    int cn = min(cnt, EDGE_CAP);
    if (tx == 0) edge_cnt[e] = cn;
    for (int i = tx; i < cn; i += blockDim.x) {
        int c = cols[i];
        int q = atomicAdd(&node_cnt[c], 1);     // device-scope, batched
        if (q < NODE_CAP) node_tgt[c * NODE_CAP + q] = e * EDGE_CAP + i;
        // overflow (q>=NODE_CAP, ~never): route edge's store to the trash slot
        edge_tgt[e * EDGE_CAP + i] = (q < NODE_CAP) ? (c * NODE_CAP + q)
                                                    : (n_nodes * NODE_CAP);
    }
}

// Coherent (cross-XCD) access helpers: sc-flagged, bypass non-coherent L1/L2.
__device__ __forceinline__ float coh_loadf(const float* p) {
    return __hip_atomic_load(p, __ATOMIC_RELAXED, __HIP_MEMORY_SCOPE_AGENT);
}
__device__ __forceinline__ void coh_storef(float* p, float v) {
    __hip_atomic_store(p, v, __ATOMIC_RELAXED, __HIP_MEMORY_SCOPE_AGENT);
}

// All SIR steps, pure dataflow (no barriers, no __syncthreads).
__global__ __launch_bounds__(COOP_THREADS) void sir_dataflow_kernel(
        const float* __restrict__ x,
        const int* __restrict__ edge_cnt, const int* __restrict__ edge_tgt,
        const int* __restrict__ node_cnt, const int* __restrict__ node_tgt,
        const float* __restrict__ beta, const float* __restrict__ gamma,
        float* __restrict__ edgeIn, float* __restrict__ nodeIn,
        float* __restrict__ out,
        int n_nodes, int n_edges, int steps) {
    const int b  = blockIdx.x;
    const int tx = threadIdx.x;

    const int node_chunk = (n_nodes + gridDim.x - 1) / gridDim.x;   // 157
    const int edge_chunk = (n_edges + gridDim.x - 1) / gridDim.x;   // 40
    const int n = b * node_chunk + tx;
    const bool own = (tx < node_chunk) && (n < n_nodes);

    const int k = tx >> 4, gl = tx & 15;       // 16 lanes per edge
    const int e = b * edge_chunk + k;
    const bool has_edge = (k < edge_chunk) && (e < n_edges);
    if (!own && !has_edge) return;             // safe: no block-level sync used

    const size_t EIN = (size_t)n_edges * EDGE_CAP;        // floats per edgeIn slice
    const size_t NIN = (size_t)n_nodes * NODE_CAP + 64;   // + trash slot slack

    // ---- preload slot targets into registers ----
    int ecnt = 0;
    int tgtE[6];
    if (has_edge) {
        ecnt = min(edge_cnt[e], EDGE_CAP);
        #pragma unroll
        for (int i = 0; i < 6; ++i) {
            int j = gl + 16 * i;
            tgtE[i] = (j < ecnt) ? edge_tgt[(size_t)e * EDGE_CAP + j] : 0;
        }
    }
    int ncnt = 0; float bet = 0.0f, gam = 0.0f;
    int tgtI[16];
    if (own) {
        ncnt = min(node_cnt[n], NODE_CAP);
        bet = beta[n]; gam = gamma[n];
        #pragma unroll
        for (int j = 0; j < 16; ++j)
            tgtI[j] = (j < ncnt) ? node_tgt[(size_t)n * NODE_CAP + j] : 0;
    }

    // ---- init: state to regs, traj[0], scatter I_0 into edgeIn[1] ----
    float s = 0.0f, iv = 0.0f, r = 0.0f;
    if (own) {
        s = x[3 * n]; iv = x[3 * n + 1]; r = x[3 * n + 2];
        out[3 * n] = s; out[3 * n + 1] = iv; out[3 * n + 2] = r;
        float* eIn1 = edgeIn + EIN;                      // t=1 slice
        #pragma unroll
        for (int j = 0; j < 16; ++j)
            if (j < ncnt) coh_storef(&eIn1[tgtI[j]], iv);
        for (int j = 16; j < ncnt; ++j)                  // rare tail
            coh_storef(&eIn1[node_tgt[(size_t)n * NODE_CAP + j]], iv);
    }

    const unsigned gsh = (unsigned)(tx & 48);            // group base in wave

    for (int t = 1; t < steps; ++t) {
        float* eInT = edgeIn + (size_t)t * EIN;
        float* nInT = nodeIn + (size_t)t * NIN;

        // ---- edge role: poll own contiguous slots, sum, scatter y ----
        if (has_edge) {
            const float* src = eInT + (size_t)e * EDGE_CAP;
            float v0, v1, v2, v3, v4, v5;
            for (;;) {
                bool ok = true;
                float a;
                a = coh_loadf(&src[gl     ]); v0 = (gl      < ecnt) ? a : 0.0f; ok &= (gl      >= ecnt) || (a >= 0.0f);
                a = coh_loadf(&src[gl + 16]); v1 = (gl + 16 < ecnt) ? a : 0.0f; ok &= (gl + 16 >= ecnt) || (a >= 0.0f);
                a = coh_loadf(&src[gl + 32]); v2 = (gl + 32 < ecnt) ? a : 0.0f; ok &= (gl + 32 >= ecnt) || (a >= 0.0f);
                a = coh_loadf(&src[gl + 48]); v3 = (gl + 48 < ecnt) ? a : 0.0f; ok &= (gl + 48 >= ecnt) || (a >= 0.0f);
                a = coh_loadf(&src[gl + 64]); v4 = (gl + 64 < ecnt) ? a : 0.0f; ok &= (gl + 64 >= ecnt) || (a >= 0.0f);
                a = coh_loadf(&src[gl + 80]); v5 = (gl + 80 < ecnt) ? a : 0.0f; ok &= (gl + 80 >= ecnt) || (a >= 0.0f);
                unsigned long long bm = __ballot(ok);
                if (((bm >> gsh) & 0xFFFFull) == 0xFFFFull) break;
                __builtin_amdgcn_s_sleep(2);
            }
            float acc = v0 + v1 + v2 + v3 + v4 + v5;     // v4-identical order
            acc += __shfl_down(acc, 8, 16);
            acc += __shfl_down(acc, 4, 16);
            acc += __shfl_down(acc, 2, 16);
            acc += __shfl_down(acc, 1, 16);
            float ysum = __shfl(acc, 0, 16);             // lane0 value, consistent
            #pragma unroll
            for (int i = 0; i < 6; ++i) {
                int j = gl + 16 * i;
                if (j < ecnt) coh_storef(&nInT[tgtE[i]], ysum);
            }
        }

        // ---- node role: poll own slots, SIR update, scatter new I ----
        if (own) {
            const float* src = nInT + (size_t)n * NODE_CAP;
            float w[16];
            bool ok;
            do {
                ok = true;
                #pragma unroll
                for (int j = 0; j < 16; ++j) {
                    w[j] = coh_loadf(&src[j]);
                    if (j < ncnt) ok &= (w[j] >= 0.0f);
                }
                if (!ok) __builtin_amdgcn_s_sleep(2);
            } while (!ok);
            float z = 0.0f;
            #pragma unroll
            for (int j = 0; j < 16; ++j)
                if (j < ncnt) z += w[j];                 // slot order 0..ncnt-1
            for (int j = 16; j < ncnt; ++j) {            // rare tail
                float vv = coh_loadf(&src[j]);
                while (vv < 0.0f) { __builtin_amdgcn_s_sleep(2); vv = coh_loadf(&src[j]); }
                z += vv;
            }
            float nc = bet * s * z;
            float nr = gam * iv;
            float s2 = fmaxf(s - nc, 0.0f);
            float i2 = fmaxf(iv + nc - nr, 0.0f);
            float r2 = fmaxf(r + nr, 0.0f);
            float inv = 1.0f / (s2 + i2 + r2);
            s = s2 * inv; iv = i2 * inv; r = r2 * inv;
            if (t + 1 < steps) {                         // feed next step's edges
                float* eInN = edgeIn + (size_t)(t + 1) * EIN;
                #pragma unroll
                for (int j = 0; j < 16; ++j)
                    if (j < ncnt) coh_storef(&eInN[tgtI[j]], iv);
                for (int j = 16; j < ncnt; ++j)
                    coh_storef(&eInN[node_tgt[(size_t)n * NODE_CAP + j]], iv);
            }
            float* ot = out + (size_t)t * n_nodes * 3 + (size_t)n * 3;
            ot[0] = s; ot[1] = iv; ot[2] = r;
        }
    }
}

extern "C" void kernel_launch(void* const* d_in, const int* in_sizes, int n_in,
                              void* d_out, int out_size, void* d_ws, size_t ws_size,
                              hipStream_t stream) {
    const float* x     = (const float*)d_in[0];
    const float* H     = (const float*)d_in[1];
    const float* beta  = (const float*)d_in[2];
    const float* gamma = (const float*)d_in[3];
    float* out = (float*)d_out;

    const int n_nodes = in_sizes[0] / 3;                 // 20000
    const int n_edges = in_sizes[1] / n_nodes;           // 5000
    const int steps   = out_size / in_sizes[0];          // 50

    const size_t EIN = (size_t)n_edges * EDGE_CAP;       // 480000 floats/slice
    const size_t NIN = (size_t)n_nodes * NODE_CAP + 64;  // 640064 floats/slice

    // workspace carve-up (all 4B elements; edgeIn offset is 16B-aligned)
    char* ws = (char*)d_ws;
    int*   edge_cnt = (int*)ws;                           ws += (size_t)n_edges * 4;
    int*   node_cnt = (int*)ws;                           ws += (size_t)n_nodes * 4;
    int*   edge_tgt = (int*)ws;                           ws += EIN * 4;
    int*   node_tgt = (int*)ws;                           ws += (size_t)n_nodes * NODE_CAP * 4;
    float* edgeIn   = (float*)ws;                         ws += (size_t)steps * EIN * 4;
    float* nodeIn   = (float*)ws;                         ws += (size_t)steps * NIN * 4;

    // 1. sentinel-fill slot buffers (contiguous edgeIn..nodeIn span) + zero counters
    {
        long long n_sent4 = (long long)steps * (long long)(EIN + NIN) / 4;
        init_ws_kernel<<<4096, 256, 0, stream>>>(edge_cnt, node_cnt,
                                                 (float4_ev*)edgeIn, n_sent4,
                                                 n_edges, n_nodes);
    }
    // 2. extract sparsity of H (the one unavoidable 400MB scan)
    build_adjacency_kernel<<<n_edges, 256, 0, stream>>>(H, edge_cnt, edge_tgt,
                                                        node_cnt, node_tgt, n_nodes);
    // 3. all SIR steps, pure dataflow (no barriers)
    sir_dataflow_kernel<<<COOP_BLOCKS, COOP_THREADS, 0, stream>>>(
        x, edge_cnt, edge_tgt, node_cnt, node_tgt, beta, gamma,
        edgeIn, nodeIn, out, n_nodes, n_edges, steps);
}

// Round 10
// 1122.568 us; speedup vs baseline: 2.3121x; 2.3121x over previous
//
#include <hip/hip_runtime.h>

// HyperNetSIR: x(N,3) f32, H(E,N) f32 0/1 mask (density 0.002), beta(N), gamma(N), steps(int)
// out: (steps, N, 3) f32 trajectory.
//
// v10 — FUSED mega-kernel (build + all steps in one launch):
//  Budget (rounds 4/6): total 981 = harness ws-poison fill ~245 (fixed)
//  + build ~250 + steps ~485. Steps structure (2 RMW-counter barriers/step,
//  register-preloaded adjacency, sc-flagged I/y exchange) is the best of 6
//  sync designs (9.9us/step) — kept verbatim. Build was 3.5x over its 67us
//  BW floor (4-wave blocks, ~20 serial load-waits each, 5000-block tail).
//  v10 builds adjacency INSIDE the persistent kernel: 256 blocks x 1024
//  threads, ~20 rows/block, software-pipelined 16B loads (next load issued
//  before current ballot; 16 waves/CU -> ~8MB in flight -> HBM-saturating),
//  then ONE release/barrier/acquire handoff (fence(agent): wbl2 + inv,
//  ~11-15us once, measured r1) makes the plain-stored adjacency visible
//  grid-wide. Kills the separate build launch, its dispatch tail, and the
//  zero->build->steps gaps. 2 dispatches total.
//  Round-8/9 lessons honored: no agent-atomic data scatter (HBM RMW streams),
//  no per-step slot buffers (working set must stay L3-resident).

#define EDGE_CAP 96   // max nodes per edge (mean 40, sigma 6.3)
#define NODE_CAP 32   // max edges per node (mean 10, sigma 3.2)
#define NIDX_REG 16   // node-adjacency indices held in registers (P(cnt>16) ~ 3%)
#define BLOCKS 256
#define THREADS 1024
#define BAR_LINES 8
#define BAR_STRIDE 128                    // u32s -> 512B between counter lines
#define BAR_UINTS (BAR_LINES * BAR_STRIDE)

typedef unsigned int uint4_ev __attribute__((ext_vector_type(4)));

__global__ void zero_ws_kernel(int* edge_cnt, int* node_cnt, unsigned* bar,
                               int n_edges, int n_nodes) {
    int i = blockIdx.x * blockDim.x + threadIdx.x;
    if (i < BAR_UINTS) bar[i] = 0u;
    if (i < n_edges) edge_cnt[i] = 0;
    if (i < n_nodes) node_cnt[i] = 0;
}

// Coherent (cross-XCD) access helpers: sc-flagged, bypass non-coherent L1/L2.
__device__ __forceinline__ float coh_loadf(const float* p) {
    return __hip_atomic_load(p, __ATOMIC_RELAXED, __HIP_MEMORY_SCOPE_AGENT);
}
__device__ __forceinline__ void coh_storef(float* p, float v) {
    __hip_atomic_store(p, v, __ATOMIC_RELAXED, __HIP_MEMORY_SCOPE_AGENT);
}

// Flat 2-hop RMW-counter barrier (v4/v6, best measured primitive).
__device__ __forceinline__ void bar_arrive(unsigned* bar) {
    asm volatile("s_waitcnt vmcnt(0)" ::: "memory");
    __syncthreads();
    if (threadIdx.x == 0)
        __hip_atomic_fetch_add(&bar[(blockIdx.x & (BAR_LINES - 1)) * BAR_STRIDE], 1u,
                               __ATOMIC_RELAXED, __HIP_MEMORY_SCOPE_AGENT);
}
__device__ __forceinline__ void bar_wait(unsigned* bar, unsigned target) {
    if (threadIdx.x == 0) {
        for (;;) {
            unsigned sum = 0;
            #pragma unroll
            for (int i = 0; i < BAR_LINES; ++i)
                sum += __hip_atomic_load(&bar[i * BAR_STRIDE], __ATOMIC_RELAXED,
                                         __HIP_MEMORY_SCOPE_AGENT);
            if (sum >= target) break;
            __builtin_amdgcn_s_sleep(1);
        }
    }
    __syncthreads();
    asm volatile("" ::: "memory");
}

// Build (rows rpb per block, software-pipelined scan) + one coherence
// handoff + all SIR steps. Requires n_nodes <= 32768 (qmask sizing),
// node_chunk <= THREADS, edge_chunk <= THREADS/16.
__global__ __launch_bounds__(THREADS) void sir_mega_kernel(
        const float* __restrict__ x, const float* __restrict__ H,
        const float* __restrict__ beta, const float* __restrict__ gamma,
        int* __restrict__ edge_cnt, int* __restrict__ edge_nodes,
        int* __restrict__ node_cnt, int* __restrict__ node_edges,
        float* __restrict__ y, float* __restrict__ I, float* __restrict__ out,
        int n_nodes, int n_edges, int steps, unsigned* bar) {
    const int b  = blockIdx.x;
    const int tx = threadIdx.x;

    __shared__ int cnt;
    __shared__ int cols[EDGE_CAP];
    __shared__ unsigned long long qmask[128];   // niter*16 <= 128

    // ================= phase 0: build adjacency for my rows =================
    const int rpb = (n_edges + gridDim.x - 1) / gridDim.x;   // 20
    const int n4 = n_nodes >> 2;
    const int niter = (n4 + THREADS - 1) / THREADS;          // 5 @ N=20000
    const int e_lo = b * rpb, e_hi = min(e_lo + rpb, n_edges);

    for (int e = e_lo; e < e_hi; ++e) {
        if (tx == 0) cnt = 0;
        const uint4_ev* row4 = (const uint4_ev*)(H + (size_t)e * n_nodes);

        // pass A: pipelined streaming scan (load i+1 issued before ballot i)
        uint4_ev vnext = {0u, 0u, 0u, 0u};
        if (tx < n4) vnext = row4[tx];
        for (int i = 0; i < niter; ++i) {
            uint4_ev v = vnext;
            int qn = (i + 1) * THREADS + tx;
            vnext = (uint4_ev){0u, 0u, 0u, 0u};
            if (i + 1 < niter && qn < n4) vnext = row4[qn];
            unsigned long long m = __ballot((v.x | v.y | v.z | v.w) != 0u);
            if ((tx & 63) == 0) qmask[i * 16 + (tx >> 6)] = m;
        }
        __syncthreads();

        // pass B: revisit only nonzero quads (L2-hot) for LDS compaction
        const int nslots = niter * 16;
        for (int sIdx = tx; sIdx < nslots; sIdx += THREADS) {
            unsigned long long m = qmask[sIdx];
            int qbase = (sIdx >> 4) * THREADS + (sIdx & 15) * 64;
            while (m) {
                int lane = __builtin_ctzll(m); m &= m - 1;
                int q = qbase + lane;
                uint4_ev v = row4[q];
                int cbase = q << 2;
                if (v.x) { int p = atomicAdd(&cnt, 1); if (p < EDGE_CAP) cols[p] = cbase; }
                if (v.y) { int p = atomicAdd(&cnt, 1); if (p < EDGE_CAP) cols[p] = cbase + 1; }
                if (v.z) { int p = atomicAdd(&cnt, 1); if (p < EDGE_CAP) cols[p] = cbase + 2; }
                if (v.w) { int p = atomicAdd(&cnt, 1); if (p < EDGE_CAP) cols[p] = cbase + 3; }
            }
        }
        if (tx == 0) {   // tail (n_nodes not multiple of 4)
            const float* row = H + (size_t)e * n_nodes;
            for (int c = n4 << 2; c < n_nodes; ++c)
                if (row[c] != 0.0f) { int p = atomicAdd(&cnt, 1); if (p < EDGE_CAP) cols[p] = c; }
        }
        __syncthreads();

        // writeout: coalesced edge list + batched device-scope node atomics
        int cn = min(cnt, EDGE_CAP);
        if (tx == 0) edge_cnt[e] = cn;
        for (int i = tx; i < cn; i += THREADS) {
            int c = cols[i];
            edge_nodes[e * EDGE_CAP + i] = c;
            int qq = atomicAdd(&node_cnt[c], 1);
            if (qq < NODE_CAP) node_edges[c * NODE_CAP + qq] = e;
        }
        __syncthreads();   // LDS reuse next row
    }

    // ======= one-time coherence handoff (wbl2 + grid barrier + inv) =======
    __builtin_amdgcn_fence(__ATOMIC_RELEASE, "agent");   // flush dirty L2 -> L3
    unsigned bars = 0;
    bar_arrive(bar); bars += gridDim.x; bar_wait(bar, bars);
    __builtin_amdgcn_fence(__ATOMIC_ACQUIRE, "agent");   // inv L1/L2: see peers' lists

    // ================= phase 1: SIR steps (v6 structure) =================
    const int node_chunk = (n_nodes + gridDim.x - 1) / gridDim.x;   // 79
    const int edge_chunk = (n_edges + gridDim.x - 1) / gridDim.x;   // 20
    const int n = b * node_chunk + tx;
    const bool own = (tx < node_chunk) && (n < n_nodes);

    const int k = tx >> 4, gl = tx & 15;       // 16 lanes per edge
    const int e = b * edge_chunk + k;
    const bool has_edge = (k < edge_chunk) && (e < n_edges);

    // preload adjacency into registers (dummy-padded: I[n_nodes]=y[n_edges]=0)
    int ecnt = 0;
    const int* en = edge_nodes;
    if (has_edge) { ecnt = min(edge_cnt[e], EDGE_CAP); en = edge_nodes + e * EDGE_CAP; }
    int eidx[6];
    #pragma unroll
    for (int i = 0; i < 6; ++i) {
        int j = i * 16 + gl;
        eidx[i] = (has_edge && j < ecnt) ? en[j] : n_nodes;
    }
    int ncnt = 0;
    const int* ne = node_edges;
    float bet = 0.0f, gam = 0.0f;
    if (own) { ncnt = min(node_cnt[n], NODE_CAP); ne = node_edges + n * NODE_CAP;
               bet = beta[n]; gam = gamma[n]; }
    int nidx[NIDX_REG];
    #pragma unroll
    for (int i = 0; i < NIDX_REG; ++i)
        nidx[i] = (own && i < ncnt) ? ne[i] : n_edges;

    // init: state to regs, publish I, dummies, traj[0]
    float s = 0.0f, iv = 0.0f, r = 0.0f;
    if (own) {
        s = x[n * 3 + 0]; iv = x[n * 3 + 1]; r = x[n * 3 + 2];
        coh_storef(&I[n], iv);
        out[n * 3 + 0] = s; out[n * 3 + 1] = iv; out[n * 3 + 2] = r;
    }
    if (b == 0 && tx == 0) { coh_storef(&I[n_nodes], 0.0f); coh_storef(&y[n_edges], 0.0f); }
    bar_arrive(bar); bars += gridDim.x; bar_wait(bar, bars);

    for (int t = 1; t < steps; ++t) {
        // edge phase: y[e] = sum I over edge members (16 lanes/edge)
        if (has_edge) {
            float a0 = coh_loadf(&I[eidx[0]]);
            float a1 = coh_loadf(&I[eidx[1]]);
            float a2 = coh_loadf(&I[eidx[2]]);
            float a3 = coh_loadf(&I[eidx[3]]);
            float a4 = coh_loadf(&I[eidx[4]]);
            float a5 = coh_loadf(&I[eidx[5]]);
            float acc = a0 + a1 + a2 + a3 + a4 + a5;   // trailing dummies add exact 0
            acc += __shfl_down(acc, 8, 16);
            acc += __shfl_down(acc, 4, 16);
            acc += __shfl_down(acc, 2, 16);
            acc += __shfl_down(acc, 1, 16);
            if (gl == 0) coh_storef(&y[e], acc);
        }
        bar_arrive(bar); bars += gridDim.x; bar_wait(bar, bars);

        // node phase: z = sum y over incident edges; SIR update in regs
        if (own) {
            float tv[NIDX_REG];
            #pragma unroll
            for (int i = 0; i < NIDX_REG; ++i) tv[i] = coh_loadf(&y[nidx[i]]);
            float z = 0.0f;
            #pragma unroll
            for (int i = 0; i < NIDX_REG; ++i) z += tv[i];   // in-order, dummies exact 0
            for (int i = NIDX_REG; i < ncnt; ++i)
                z += coh_loadf(&y[ne[i]]);                   // rare tail
            float nc = bet * s * z;
            float nr = gam * iv;
            float s2 = fmaxf(s - nc, 0.0f);
            float i2 = fmaxf(iv + nc - nr, 0.0f);
            float r2 = fmaxf(r + nr, 0.0f);
            float inv = 1.0f / (s2 + i2 + r2);
            s = s2 * inv; iv = i2 * inv; r = r2 * inv;
            coh_storef(&I[n], iv);
        }
        bar_arrive(bar); bars += gridDim.x;
        if (own) {   // coalesced traj store overlaps other blocks' spin
            float* ot = out + (size_t)t * n_nodes * 3 + (size_t)n * 3;
            ot[0] = s; ot[1] = iv; ot[2] = r;
        }
        if (t + 1 < steps) bar_wait(bar, bars);
    }
}

extern "C" void kernel_launch(void* const* d_in, const int* in_sizes, int n_in,
                              void* d_out, int out_size, void* d_ws, size_t ws_size,
                              hipStream_t stream) {
    const float* x     = (const float*)d_in[0];
    const float* H     = (const float*)d_in[1];
    const float* beta  = (const float*)d_in[2];
    const float* gamma = (const float*)d_in[3];
    float* out = (float*)d_out;

    const int n_nodes = in_sizes[0] / 3;                 // 20000
    const int n_edges = in_sizes[1] / n_nodes;           // 5000
    const int steps   = out_size / in_sizes[0];          // 50

    // workspace carve-up (ints/floats are both 4B)
    char* ws = (char*)d_ws;
    unsigned* bar     = (unsigned*)ws;                    ws += (size_t)BAR_UINTS * 4;
    int*   edge_cnt   = (int*)ws;                         ws += (size_t)n_edges * 4;
    int*   node_cnt   = (int*)ws;                         ws += (size_t)n_nodes * 4;
    int*   edge_nodes = (int*)ws;                         ws += (size_t)n_edges * EDGE_CAP * 4;
    int*   node_edges = (int*)ws;                         ws += (size_t)n_nodes * NODE_CAP * 4;
    float* y          = (float*)ws;                       ws += ((size_t)n_edges + 1) * 4;
    float* I          = (float*)ws;                       ws += ((size_t)n_nodes + 1) * 4;

    // 1. zero counters + barrier (ws is poisoned 0xAA each call)
    {
        int mx = max(n_edges, max(n_nodes, (int)BAR_UINTS));
        zero_ws_kernel<<<(mx + 255) / 256, 256, 0, stream>>>(edge_cnt, node_cnt, bar,
                                                             n_edges, n_nodes);
    }
    // 2. build + handoff + all SIR steps, one persistent launch
    sir_mega_kernel<<<BLOCKS, THREADS, 0, stream>>>(
        x, H, beta, gamma, edge_cnt, edge_nodes, node_cnt, node_edges,
        y, I, out, n_nodes, n_edges, steps, bar);
}

// Round 13
// 1015.094 us; speedup vs baseline: 2.5569x; 1.1059x over previous
//
#include <hip/hip_runtime.h>

// HyperNetSIR: x(N,3) f32, H(E,N) f32 0/1 mask (density 0.002), beta(N), gamma(N), steps(int)
// out: (steps, N, 3) f32 trajectory.
//
// v11c — LDS bulk-broadcast steps (two infra-flake resubmits of v11):
//  10-round findings: step time 9.9us invariant to barrier/block/wave
//  choices; scatter-RMW and dataflow variants are traffic-bound. Residual
//  cost = per-phase scattered-gather SKEW serialized by max-of-N barriers,
//  twice per step. v11 removes scattered coherent access entirely:
//   - I (80KB) and y (20KB) fit in LDS. Each of 64 blocks bulk-reads the
//     WHOLE I array (contiguous sc loads, uniform) into LDS, edge sums are
//     LDS gathers (register-preloaded indices), publishes a 316B contiguous
//     y-chunk; barrier; bulk-reads all y to LDS, node-updates from LDS,
//     publishes a 1.2KB contiguous I-chunk; barrier.
//   - cross-XCD traffic: 6.4MB/step bulk, L3-resident (r9 lesson).
//   - barrier: v4 flat RMW-counter, 8 lines (best measured primitive).
//  build: v6 two-pass standalone (~245us; 5 variants time-invariant).
//  Requires n_nodes <= 20000, n_edges <= 5000 (LDS sizing; problem constants).

#define EDGE_CAP 96   // max nodes per edge (mean 40, sigma 6.3)
#define NODE_CAP 32   // max edges per node (mean 10, sigma 3.2)
#define NIDX_REG 16   // node-adjacency indices held in registers (P(cnt>16) ~ 3%)
#define BLOCKS 64
#define THREADS 1024
#define BAR_LINES 8
#define BAR_STRIDE 128                    // u32s -> 512B between counter lines
#define BAR_UINTS (BAR_LINES * BAR_STRIDE)
#define LDS_NODES 20000                   // problem constant ceiling
#define LDS_EDGES 5000

typedef unsigned int uint4_ev __attribute__((ext_vector_type(4)));

__global__ void zero_ws_kernel(int* edge_cnt, int* node_cnt, unsigned* bar,
                               int n_edges, int n_nodes) {
    int i = blockIdx.x * blockDim.x + threadIdx.x;
    if (i < BAR_UINTS) bar[i] = 0u;
    if (i < n_edges) edge_cnt[i] = 0;
    if (i < n_nodes) node_cnt[i] = 0;
}

// One block (256 threads) per edge row (v6 two-pass).
__global__ void build_adjacency_kernel(const float* __restrict__ H,
                                       int* __restrict__ edge_cnt,
                                       int* __restrict__ edge_nodes,
                                       int* __restrict__ node_cnt,
                                       int* __restrict__ node_edges,
                                       int n_nodes) {
    __shared__ int cnt;
    __shared__ int cols[EDGE_CAP];
    __shared__ unsigned long long qmask[128];   // supports n_nodes <= 32768
    const int e  = blockIdx.x;
    const int tx = threadIdx.x;
    if (tx == 0) cnt = 0;
    const float* row = H + (size_t)e * n_nodes;
    const uint4_ev* row4 = (const uint4_ev*)row;
    const int n4 = n_nodes >> 2;
    const int niter = (n4 + 255) >> 8;

    for (int i = 0; i < niter; ++i) {
        int q = (i << 8) + tx;
        uint4_ev v = {0u, 0u, 0u, 0u};
        if (q < n4) v = row4[q];
        unsigned long long m = __ballot((v.x | v.y | v.z | v.w) != 0u);
        if ((tx & 63) == 0) qmask[(i << 2) + (tx >> 6)] = m;
    }
    __syncthreads();

    const int nslots = niter << 2;
    for (int sIdx = tx; sIdx < nslots; sIdx += blockDim.x) {
        unsigned long long m = qmask[sIdx];
        int qbase = ((sIdx >> 2) << 8) + ((sIdx & 3) << 6);
        while (m) {
            int lane = __builtin_ctzll(m); m &= m - 1;
            int q = qbase + lane;
            uint4_ev v = row4[q];               // L2 hit
            int cbase = q << 2;
            if (v.x) { int p = atomicAdd(&cnt, 1); if (p < EDGE_CAP) cols[p] = cbase; }
            if (v.y) { int p = atomicAdd(&cnt, 1); if (p < EDGE_CAP) cols[p] = cbase + 1; }
            if (v.z) { int p = atomicAdd(&cnt, 1); if (p < EDGE_CAP) cols[p] = cbase + 2; }
            if (v.w) { int p = atomicAdd(&cnt, 1); if (p < EDGE_CAP) cols[p] = cbase + 3; }
        }
    }
    if (tx == 0) {   // tail (n_nodes not multiple of 4)
        for (int c = n4 << 2; c < n_nodes; ++c)
            if (row[c] != 0.0f) { int p = atomicAdd(&cnt, 1); if (p < EDGE_CAP) cols[p] = c; }
    }
    __syncthreads();

    int cn = min(cnt, EDGE_CAP);
    if (tx == 0) edge_cnt[e] = cn;
    for (int i = tx; i < cn; i += blockDim.x) {
        int c = cols[i];
        edge_nodes[e * EDGE_CAP + i] = c;
        int q = atomicAdd(&node_cnt[c], 1);     // device-scope, batched
        if (q < NODE_CAP) node_edges[c * NODE_CAP + q] = e;
    }
}

// Coherent (cross-XCD) access helpers: sc-flagged, bypass non-coherent L1/L2.
__device__ __forceinline__ float coh_loadf(const float* p) {
    return __hip_atomic_load(p, __ATOMIC_RELAXED, __HIP_MEMORY_SCOPE_AGENT);
}
__device__ __forceinline__ void coh_storef(float* p, float v) {
    __hip_atomic_store(p, v, __ATOMIC_RELAXED, __HIP_MEMORY_SCOPE_AGENT);
}

// Flat 2-hop RMW-counter barrier (v4/v6, best measured primitive).
__device__ __forceinline__ void bar_arrive(unsigned* bar) {
    asm volatile("s_waitcnt vmcnt(0)" ::: "memory");
    __syncthreads();
    if (threadIdx.x == 0)
        __hip_atomic_fetch_add(&bar[(blockIdx.x & (BAR_LINES - 1)) * BAR_STRIDE], 1u,
                               __ATOMIC_RELAXED, __HIP_MEMORY_SCOPE_AGENT);
}
__device__ __forceinline__ void bar_wait(unsigned* bar, unsigned target) {
    if (threadIdx.x == 0) {
        for (;;) {
            unsigned sum = 0;
            #pragma unroll
            for (int i = 0; i < BAR_LINES; ++i)
                sum += __hip_atomic_load(&bar[i * BAR_STRIDE], __ATOMIC_RELAXED,
                                         __HIP_MEMORY_SCOPE_AGENT);
            if (sum >= target) break;
            __builtin_amdgcn_s_sleep(1);
        }
    }
    __syncthreads();
    asm volatile("" ::: "memory");
}

// All SIR steps; I/y mirrored into LDS per phase via bulk coherent reads.
// Requires n_nodes <= LDS_NODES, n_edges <= LDS_EDGES, gridDim == BLOCKS.
__global__ __launch_bounds__(THREADS) void sir_lds_kernel(
        const float* __restrict__ x,
        const int* __restrict__ edge_cnt, const int* __restrict__ edge_nodes,
        const int* __restrict__ node_cnt, const int* __restrict__ node_edges,
        const float* __restrict__ beta, const float* __restrict__ gamma,
        float* __restrict__ y, float* __restrict__ I, float* __restrict__ out,
        int n_nodes, int n_edges, int steps, unsigned* bar) {
    __shared__ float I_lds[LDS_NODES + 1];   // +1 dummy slot (reads 0)
    __shared__ float y_lds[LDS_EDGES + 1];
    const int b  = blockIdx.x;
    const int tx = threadIdx.x;

    const int node_chunk = (n_nodes + gridDim.x - 1) / gridDim.x;   // 313
    const int edge_chunk = (n_edges + gridDim.x - 1) / gridDim.x;   // 79
    const int n = b * node_chunk + tx;
    const bool own = (tx < node_chunk) && (n < n_nodes);

    const int k = tx >> 4, gl = tx & 15;        // 64 groups x 16 lanes
    const int ebase = b * edge_chunk;
    const int elim  = min(ebase + edge_chunk, n_edges);
    const int e0 = ebase + k;          const bool he0 = (e0 < elim);
    const int e1 = ebase + k + 64;     const bool he1 = (k + 64 < edge_chunk) && (e1 < elim);

    // dummy slots (never overwritten by bulk loads)
    if (tx == 0) { I_lds[n_nodes] = 0.0f; y_lds[n_edges] = 0.0f; }

    // ---- preload adjacency into registers (dummy -> LDS zero slots) ----
    int ecnt0 = 0, ecnt1 = 0;
    int eidx0[6], eidx1[6];
    if (he0) ecnt0 = min(edge_cnt[e0], EDGE_CAP);
    if (he1) ecnt1 = min(edge_cnt[e1], EDGE_CAP);
    {
        const int* en0 = edge_nodes + (size_t)e0 * EDGE_CAP;
        const int* en1 = edge_nodes + (size_t)e1 * EDGE_CAP;
        #pragma unroll
        for (int i = 0; i < 6; ++i) {
            int j = gl + 16 * i;
            eidx0[i] = (he0 && j < ecnt0) ? en0[j] : n_nodes;
            eidx1[i] = (he1 && j < ecnt1) ? en1[j] : n_nodes;
        }
    }
    int ncnt = 0;
    const int* ne = node_edges;
    float bet = 0.0f, gam = 0.0f;
    if (own) { ncnt = min(node_cnt[n], NODE_CAP); ne = node_edges + (size_t)n * NODE_CAP;
               bet = beta[n]; gam = gamma[n]; }
    int nidx[NIDX_REG];
    #pragma unroll
    for (int i = 0; i < NIDX_REG; ++i)
        nidx[i] = (own && i < ncnt) ? ne[i] : n_edges;

    // ---- init: state to regs, publish I0 chunk, traj[0] ----
    float s = 0.0f, iv = 0.0f, r = 0.0f;
    if (own) {
        s = x[n * 3 + 0]; iv = x[n * 3 + 1]; r = x[n * 3 + 2];
        coh_storef(&I[n], iv);
        out[n * 3 + 0] = s; out[n * 3 + 1] = iv; out[n * 3 + 2] = r;
    }
    unsigned bars = 0;
    bar_arrive(bar); bars += gridDim.x; bar_wait(bar, bars);

    for (int t = 1; t < steps; ++t) {
        // ---- bulk-broadcast I -> LDS (uniform contiguous coherent reads) ----
        for (int i0 = tx; i0 < n_nodes; i0 += 4 * THREADS) {
            int i1 = i0 + THREADS, i2 = i0 + 2 * THREADS, i3 = i0 + 3 * THREADS;
            float a0 = coh_loadf(&I[i0]);
            float a1 = (i1 < n_nodes) ? coh_loadf(&I[i1]) : 0.0f;
            float a2 = (i2 < n_nodes) ? coh_loadf(&I[i2]) : 0.0f;
            float a3 = (i3 < n_nodes) ? coh_loadf(&I[i3]) : 0.0f;
            I_lds[i0] = a0;
            if (i1 < n_nodes) I_lds[i1] = a1;
            if (i2 < n_nodes) I_lds[i2] = a2;
            if (i3 < n_nodes) I_lds[i3] = a3;
        }
        __syncthreads();

        // ---- edge phase: LDS gathers, publish tiny contiguous y chunk ----
        if (he0) {
            float acc = I_lds[eidx0[0]] + I_lds[eidx0[1]] + I_lds[eidx0[2]]
                      + I_lds[eidx0[3]] + I_lds[eidx0[4]] + I_lds[eidx0[5]];
            acc += __shfl_down(acc, 8, 16);
            acc += __shfl_down(acc, 4, 16);
            acc += __shfl_down(acc, 2, 16);
            acc += __shfl_down(acc, 1, 16);
            if (gl == 0) coh_storef(&y[e0], acc);
        }
        if (he1) {
            float acc = I_lds[eidx1[0]] + I_lds[eidx1[1]] + I_lds[eidx1[2]]
                      + I_lds[eidx1[3]] + I_lds[eidx1[4]] + I_lds[eidx1[5]];
            acc += __shfl_down(acc, 8, 16);
            acc += __shfl_down(acc, 4, 16);
            acc += __shfl_down(acc, 2, 16);
            acc += __shfl_down(acc, 1, 16);
            if (gl == 0) coh_storef(&y[e1], acc);
        }
        bar_arrive(bar); bars += gridDim.x; bar_wait(bar, bars);

        // ---- bulk-broadcast y -> LDS ----
        for (int i0 = tx; i0 < n_edges; i0 += 4 * THREADS) {
            int i1 = i0 + THREADS, i2 = i0 + 2 * THREADS, i3 = i0 + 3 * THREADS;
            float a0 = coh_loadf(&y[i0]);
            float a1 = (i1 < n_edges) ? coh_loadf(&y[i1]) : 0.0f;
            float a2 = (i2 < n_edges) ? coh_loadf(&y[i2]) : 0.0f;
            float a3 = (i3 < n_edges) ? coh_loadf(&y[i3]) : 0.0f;
            y_lds[i0] = a0;
            if (i1 < n_edges) y_lds[i1] = a1;
            if (i2 < n_edges) y_lds[i2] = a2;
            if (i3 < n_edges) y_lds[i3] = a3;
        }
        __syncthreads();

        // ---- node phase: LDS gathers, SIR update in regs, publish I chunk ----
        if (own) {
            float tv[NIDX_REG];
            #pragma unroll
            for (int i = 0; i < NIDX_REG; ++i) tv[i] = y_lds[nidx[i]];
            float z = 0.0f;
            #pragma unroll
            for (int i = 0; i < NIDX_REG; ++i) z += tv[i];   // in-order, dummies exact 0
            for (int i = NIDX_REG; i < ncnt; ++i) z += y_lds[ne[i]];  // rare tail
            float nc = bet * s * z;
            float nr = gam * iv;
            float s2 = fmaxf(s - nc, 0.0f);
            float i2 = fmaxf(iv + nc - nr, 0.0f);
            float r2 = fmaxf(r + nr, 0.0f);
            float inv = 1.0f / (s2 + i2 + r2);
            s = s2 * inv; iv = i2 * inv; r = r2 * inv;
            coh_storef(&I[n], iv);
        }
        bar_arrive(bar); bars += gridDim.x;
        if (own) {   // coalesced traj store overlaps other blocks' spin
            float* ot = out + (size_t)t * n_nodes * 3 + (size_t)n * 3;
            ot[0] = s; ot[1] = iv; ot[2] = r;
        }
        if (t + 1 < steps) bar_wait(bar, bars);
    }
}

extern "C" void kernel_launch(void* const* d_in, const int* in_sizes, int n_in,
                              void* d_out, int out_size, void* d_ws, size_t ws_size,
                              hipStream_t stream) {
    const float* x     = (const float*)d_in[0];
    const float* H     = (const float*)d_in[1];
    const float* beta  = (const float*)d_in[2];
    const float* gamma = (const float*)d_in[3];
    float* out = (float*)d_out;

    const int n_nodes = in_sizes[0] / 3;                 // 20000
    const int n_edges = in_sizes[1] / n_nodes;           // 5000
    const int steps   = out_size / in_sizes[0];          // 50

    // workspace carve-up (ints/floats are both 4B)
    char* ws = (char*)d_ws;
    unsigned* bar     = (unsigned*)ws;                    ws += (size_t)BAR_UINTS * 4;
    int*   edge_cnt   = (int*)ws;                         ws += (size_t)n_edges * 4;
    int*   node_cnt   = (int*)ws;                         ws += (size_t)n_nodes * 4;
    int*   edge_nodes = (int*)ws;                         ws += (size_t)n_edges * EDGE_CAP * 4;
    int*   node_edges = (int*)ws;                         ws += (size_t)n_nodes * NODE_CAP * 4;
    float* y          = (float*)ws;                       ws += (size_t)n_edges * 4;
    float* I          = (float*)ws;                       ws += (size_t)n_nodes * 4;

    // 1. zero counters + barrier (ws is poisoned 0xAA each call)
    {
        int mx = max(n_edges, max(n_nodes, (int)BAR_UINTS));
        zero_ws_kernel<<<(mx + 255) / 256, 256, 0, stream>>>(edge_cnt, node_cnt, bar,
                                                             n_edges, n_nodes);
    }
    // 2. extract sparsity of H (the one unavoidable 400MB scan)
    build_adjacency_kernel<<<n_edges, 256, 0, stream>>>(H, edge_cnt, edge_nodes,
                                                        node_cnt, node_edges, n_nodes);
    // 3. all SIR steps, LDS bulk-broadcast structure
    sir_lds_kernel<<<BLOCKS, THREADS, 0, stream>>>(
        x, edge_cnt, edge_nodes, node_cnt, node_edges, beta, gamma,
        y, I, out, n_nodes, n_edges, steps, bar);
}